// Round 12
// baseline (47.347 us; speedup 1.0000x reference)
//
#include <hip/hip_runtime.h>
#include <math.h>

#define NPTS 50000
#define KNBR 16
#define LAT  16
#define NCLS 64
#define NB   4

#define ENC1_CHUNKS 5
#define ENC1_BLOCKS (200 * ENC1_CHUNKS)      // 1000
#define NLANES (NPTS * 4)                    // 200000
#define CONV_BLOCKS ((NLANES + 255) / 256)   // 782
#define MLP_BLOCKS 50

__device__ __forceinline__ float sigmoidf_(float v) { return 1.0f / (1.0f + expf(-v)); }

// ---------------- Kernel 1: x @ enc1_w.T partials (r11-exact) ----------------
__global__ __launch_bounds__(256) void k_enc1(const float* __restrict__ x,
                                              const float* __restrict__ w,
                                              float* __restrict__ part) {
  const int NV4 = NPTS / 4;           // 12500 float4 per row
  const int CV  = NV4 / ENC1_CHUNKS;  // 2500 float4 per chunk
  int bid = blockIdx.x;
  int j = bid / ENC1_CHUNKS;
  int chunk = bid - j * ENC1_CHUNKS;
  int t = threadIdx.x;
  const float4* wv = (const float4*)(w + (size_t)j * NPTS);
  const float4* xv = (const float4*)x;
  float a0 = 0.f, a1 = 0.f, a2 = 0.f, a3 = 0.f;
  int vend = (chunk + 1) * CV;
#pragma unroll 2
  for (int v = chunk * CV + t; v < vend; v += 256) {
    float4 wf = wv[v];
    float4 x0 = xv[v];
    float4 x1 = xv[NV4 + v];
    float4 x2 = xv[2 * NV4 + v];
    float4 x3 = xv[3 * NV4 + v];
    a0 += wf.x * x0.x + wf.y * x0.y + wf.z * x0.z + wf.w * x0.w;
    a1 += wf.x * x1.x + wf.y * x1.y + wf.z * x1.z + wf.w * x1.w;
    a2 += wf.x * x2.x + wf.y * x2.y + wf.z * x2.z + wf.w * x2.w;
    a3 += wf.x * x3.x + wf.y * x3.y + wf.z * x3.z + wf.w * x3.w;
  }
#pragma unroll
  for (int off = 32; off > 0; off >>= 1) {
    a0 += __shfl_down(a0, off);
    a1 += __shfl_down(a1, off);
    a2 += __shfl_down(a2, off);
    a3 += __shfl_down(a3, off);
  }
  __shared__ float red[4][4];
  int wid = t >> 6;
  if ((t & 63) == 0) {
    red[wid][0] = a0; red[wid][1] = a1; red[wid][2] = a2; red[wid][3] = a3;
  }
  __syncthreads();
  if (t < 4) {
    float s = red[0][t] + red[1][t] + red[2][t] + red[3][t];
    part[j * 20 + chunk * 4 + t] = s;
  }
}

// ---------------- Kernel 2: fused MLP A..E (50 blocks, manual grid barriers) ----------------
// 50 blocks <= 256 CUs -> all resident immediately; spin barrier cannot deadlock.
// Phase 0 preloads D/E weights into registers so their fetch overlaps block 0's
// serial ABC chain. Barrier pattern = r3/r4's proven relaxed-spin + acquire.
__global__ __launch_bounds__(256) void k_mlpFused(
    const float* __restrict__ part,
    const float* __restrict__ enc1_b,
    const float* __restrict__ enc2_w,
    const float* __restrict__ enc2_b,
    const float* __restrict__ h0_w,
    const float* __restrict__ h0_b,
    const float* __restrict__ h1_w,
    const float* __restrict__ h1_b,
    const float* __restrict__ h2_w,
    const float* __restrict__ h2_b,
    float* __restrict__ w_enc,
    float* __restrict__ w_hcl,
    float* __restrict__ z0g,
    float* __restrict__ z1g,
    unsigned int* __restrict__ bar1,
    unsigned int* __restrict__ bar2)
{
  __shared__ __align__(16) float4 s_e2w[800];      // enc2_w (block 0 only)
  __shared__ __align__(16) float s_h0w[200 * 20];  // h0_w, 80B row pitch (block 0 only)
  __shared__ float s_h[NB][200];
  __shared__ float s_enc[NB][LAT];
  __shared__ __align__(16) float4 s_z0[200];
  __shared__ __align__(16) float4 s_z1[200];

  int t = threadIdx.x, bid = blockIdx.x;
  int wv = t >> 6, l = t & 63;
  int row = bid * 4 + wv;                 // D-row / E-class index

  // ---- Phase 0: issue weight preloads (overlap everything downstream) ----
  float4 wD = make_float4(0.f, 0.f, 0.f, 0.f);
  float4 wE = make_float4(0.f, 0.f, 0.f, 0.f);
  if (l < 50) wD = ((const float4*)(h1_w + row * 200))[l];
  if (bid < 16 && l < 50) wE = ((const float4*)(h2_w + row * 200))[l];

  if (bid == 0) {
    // Stage enc2_w + h0_w to LDS; loads issue concurrently with part loads.
    for (int o = t; o < 800; o += 256) {
      float4 we = ((const float4*)enc2_w)[o];
      float4 wh = ((const float4*)h0_w)[o];
      s_e2w[o] = we;
      int jo = o >> 2, c = o & 3;
      *(float4*)&s_h0w[jo * 20 + c * 4] = wh;
    }
    // A: h = sigmoid(sum of 5 chunk partials + bias)
    for (int o = t; o < 800; o += 256) {
      int j = o >> 2, b = o & 3;
      float v = part[j * 20 + 0 + b] + part[j * 20 + 4 + b] + part[j * 20 + 8 + b] +
                part[j * 20 + 12 + b] + part[j * 20 + 16 + b] + enc1_b[j];
      s_h[b][j] = sigmoidf_(v);
    }
    __syncthreads();
    // B: encoded = h @ enc2_w.T + enc2_b (64 outputs x 4 lanes, LDS weights)
    {
      int g = t >> 2, p = t & 3;
      int b = g >> 4, i = g & 15;
      float s = 0.f;
      for (int f = p; f < 50; f += 4) {
        float4 w = s_e2w[i * 50 + f];
        int j = f * 4;
        s += w.x * s_h[b][j] + w.y * s_h[b][j + 1] + w.z * s_h[b][j + 2] + w.w * s_h[b][j + 3];
      }
      s += __shfl_xor(s, 1, 4);
      s += __shfl_xor(s, 2, 4);
      if (p == 0) {
        s += enc2_b[i];
        s_enc[b][i] = s;
        w_enc[b * LAT + i] = s;
      }
    }
    __syncthreads();
    // C: z0 = swish(encoded @ h0_w.T + h0_b) -> z0g[j*4+b]
    for (int o = t; o < 800; o += 256) {
      int jo = o >> 2, b = o & 3;
      const float* hw = &s_h0w[jo * 20];
      float4 w0 = *(const float4*)&hw[0];
      float4 w1 = *(const float4*)&hw[4];
      float4 w2 = *(const float4*)&hw[8];
      float4 w3 = *(const float4*)&hw[12];
      float s = h0_b[jo];
      s += w0.x * s_enc[b][0] + w0.y * s_enc[b][1] + w0.z * s_enc[b][2] + w0.w * s_enc[b][3];
      s += w1.x * s_enc[b][4] + w1.y * s_enc[b][5] + w1.z * s_enc[b][6] + w1.w * s_enc[b][7];
      s += w2.x * s_enc[b][8] + w2.y * s_enc[b][9] + w2.z * s_enc[b][10] + w2.w * s_enc[b][11];
      s += w3.x * s_enc[b][12] + w3.y * s_enc[b][13] + w3.z * s_enc[b][14] + w3.w * s_enc[b][15];
      z0g[jo * 4 + b] = s * sigmoidf_(s);
    }
  }

  // ---- Grid barrier 1 (z0g ready) ----
  if (t == 0) {
    __threadfence();
    __hip_atomic_fetch_add(bar1, 1u, __ATOMIC_ACQ_REL, __HIP_MEMORY_SCOPE_AGENT);
    while (__hip_atomic_load(bar1, __ATOMIC_RELAXED, __HIP_MEMORY_SCOPE_AGENT) < (unsigned)MLP_BLOCKS)
      __builtin_amdgcn_s_sleep(1);
    (void)__hip_atomic_load(bar1, __ATOMIC_ACQUIRE, __HIP_MEMORY_SCOPE_AGENT);
  }
  __syncthreads();

  // ---- D: z1 rows (weights already in wD registers) ----
  if (t < 200) s_z0[t] = ((const float4*)z0g)[t];
  __syncthreads();
  {
    float d0 = 0.f, d1 = 0.f, d2 = 0.f, d3 = 0.f;
    if (l < 50) {
      float4 z0 = s_z0[4 * l + 0], z1 = s_z0[4 * l + 1];
      float4 z2 = s_z0[4 * l + 2], z3 = s_z0[4 * l + 3];
      d0 = wD.x * z0.x + wD.y * z1.x + wD.z * z2.x + wD.w * z3.x;
      d1 = wD.x * z0.y + wD.y * z1.y + wD.z * z2.y + wD.w * z3.y;
      d2 = wD.x * z0.z + wD.y * z1.z + wD.z * z2.z + wD.w * z3.z;
      d3 = wD.x * z0.w + wD.y * z1.w + wD.z * z2.w + wD.w * z3.w;
    }
#pragma unroll
    for (int m = 32; m > 0; m >>= 1) {
      d0 += __shfl_xor(d0, m, 64);
      d1 += __shfl_xor(d1, m, 64);
      d2 += __shfl_xor(d2, m, 64);
      d3 += __shfl_xor(d3, m, 64);
    }
    if (l == 0) {
      float bb = h1_b[row];
      float s;
      s = d0 + bb; z1g[row * 4 + 0] = s * sigmoidf_(s);
      s = d1 + bb; z1g[row * 4 + 1] = s * sigmoidf_(s);
      s = d2 + bb; z1g[row * 4 + 2] = s * sigmoidf_(s);
      s = d3 + bb; z1g[row * 4 + 3] = s * sigmoidf_(s);
    }
  }

  // ---- Grid barrier 2 (z1g ready); blocks 16..49 arrive and exit ----
  if (t == 0) {
    __threadfence();
    __hip_atomic_fetch_add(bar2, 1u, __ATOMIC_ACQ_REL, __HIP_MEMORY_SCOPE_AGENT);
  }
  if (bid >= 16) return;
  if (t == 0) {
    while (__hip_atomic_load(bar2, __ATOMIC_RELAXED, __HIP_MEMORY_SCOPE_AGENT) < (unsigned)MLP_BLOCKS)
      __builtin_amdgcn_s_sleep(1);
    (void)__hip_atomic_load(bar2, __ATOMIC_ACQUIRE, __HIP_MEMORY_SCOPE_AGENT);
  }
  __syncthreads();

  // ---- E: H_cluster (weights already in wE registers); class c = row ----
  if (t < 200) s_z1[t] = ((const float4*)z1g)[t];
  __syncthreads();
  {
    float e0 = 0.f, e1 = 0.f, e2 = 0.f, e3 = 0.f;
    if (l < 50) {
      float4 za = s_z1[4 * l + 0], zb = s_z1[4 * l + 1];
      float4 zc = s_z1[4 * l + 2], zd = s_z1[4 * l + 3];
      e0 = wE.x * za.x + wE.y * zb.x + wE.z * zc.x + wE.w * zd.x;
      e1 = wE.x * za.y + wE.y * zb.y + wE.z * zc.y + wE.w * zd.y;
      e2 = wE.x * za.z + wE.y * zb.z + wE.z * zc.z + wE.w * zd.z;
      e3 = wE.x * za.w + wE.y * zb.w + wE.z * zc.w + wE.w * zd.w;
    }
#pragma unroll
    for (int m = 32; m > 0; m >>= 1) {
      e0 += __shfl_xor(e0, m, 64);
      e1 += __shfl_xor(e1, m, 64);
      e2 += __shfl_xor(e2, m, 64);
      e3 += __shfl_xor(e3, m, 64);
    }
    if (l == 0) {
      float sb = h2_b[row];
      w_hcl[0 * NCLS + row] = sigmoidf_(0.01f * (e0 + sb));
      w_hcl[1 * NCLS + row] = sigmoidf_(0.01f * (e1 + sb));
      w_hcl[2 * NCLS + row] = sigmoidf_(0.01f * (e2 + sb));
      w_hcl[3 * NCLS + row] = sigmoidf_(0.01f * (e3 + sb));
    }
  }
}

// ---------------- Kernel 3: neighbour conv (r11-exact) ----------------
__global__ __launch_bounds__(256, 4) void k_conv(const int* __restrict__ nid,
                                                 const float* __restrict__ nd,
                                                 const int* __restrict__ labels,
                                                 const float* __restrict__ dec_w,
                                                 const float* __restrict__ dec_b,
                                                 const float* __restrict__ Bp,
                                                 const float* __restrict__ w_enc,
                                                 const float* __restrict__ w_hcl,
                                                 float* __restrict__ out) {
  __shared__ float s_enc[NB * LAT];
  __shared__ float s_hcl[NB * NCLS];
  int t = threadIdx.x;
  if (t < NB * LAT) s_enc[t] = w_enc[t];
  s_hcl[t] = w_hcl[t];
  __syncthreads();

  int gidx = blockIdx.x * 256 + t;       // = n*4 + q
  int n = gidx >> 2;
  int q = t & 3;
  if (n >= NPTS) return;

  const float4* nd4 = (const float4*)nd + (size_t)n * 4;
  const int4*   ni4 = (const int4*)nid + (size_t)n * 4;
  float dA[16];
  int nA[16];
#pragma unroll
  for (int a = 0; a < 4; ++a) {
    float4 v = nd4[a];
    int4  iv = ni4[a];
    dA[a * 4 + 0] = v.x * v.x; dA[a * 4 + 1] = v.y * v.y;
    dA[a * 4 + 2] = v.z * v.z; dA[a * 4 + 3] = v.w * v.w;
    nA[a * 4 + 0] = iv.x; nA[a * 4 + 1] = iv.y;
    nA[a * 4 + 2] = iv.z; nA[a * 4 + 3] = iv.w;
  }

  int lab = labels[n];
  float decb = dec_b[n];
  float Bv = Bp[0];

  const float4* dw4 = (const float4*)dec_w;
  float4 dwp[8];
#pragma unroll
  for (int k = 0; k < 8; ++k)
    dwp[k] = dw4[(size_t)nA[k] * 4 + q];

  float inv0 = 1.0f / (4.0f * Bv * Bv);

  float ivd[4][4];
#pragma unroll
  for (int b = 0; b < 4; ++b) {
    float H = s_hcl[b * NCLS + lab];
    float base = 1.0f - 0.5f * H;
    float rb = __builtin_amdgcn_rcpf(base * base);   // base^-2
    float rb2 = rb * rb;
    float rb4 = rb2 * rb2;
    float rb8 = rb4 * rb4;
    float start = inv0;
    if (q & 1) start *= rb4;
    if (q & 2) start *= rb8;
    ivd[b][0] = start;
    ivd[b][1] = ivd[b][0] * rb;
    ivd[b][2] = ivd[b][1] * rb;
    ivd[b][3] = ivd[b][2] * rb;
  }

  float sden[4][4], num[4][4];
#pragma unroll
  for (int b = 0; b < 4; ++b)
#pragma unroll
    for (int j = 0; j < 4; ++j) { sden[b][j] = 0.f; num[b][j] = 0.f; }

#pragma unroll
  for (int k = 0; k < KNBR; ++k) {
    float4 dw = (k < 8) ? dwp[k] : dw4[(size_t)nA[k] * 4 + q];
    float d2k = dA[k];
#pragma unroll
    for (int b = 0; b < 4; ++b) {
      float w0 = fmaxf(fmaf(-d2k, ivd[b][0], 1.0f), 0.0f);
      float w1 = fmaxf(fmaf(-d2k, ivd[b][1], 1.0f), 0.0f);
      float w2 = fmaxf(fmaf(-d2k, ivd[b][2], 1.0f), 0.0f);
      float w3 = fmaxf(fmaf(-d2k, ivd[b][3], 1.0f), 0.0f);
      sden[b][0] += w0; num[b][0] = fmaf(w0, dw.x, num[b][0]);
      sden[b][1] += w1; num[b][1] = fmaf(w1, dw.y, num[b][1]);
      sden[b][2] += w2; num[b][2] = fmaf(w2, dw.z, num[b][2]);
      sden[b][3] += w3; num[b][3] = fmaf(w3, dw.w, num[b][3]);
    }
  }

  float acc[4];
#pragma unroll
  for (int b = 0; b < 4; ++b) {
    float a = 0.f;
#pragma unroll
    for (int j = 0; j < 4; ++j) {
      a = fmaf(s_enc[b * LAT + q * 4 + j] * __builtin_amdgcn_rcpf(sden[b][j]),
               num[b][j], a);
    }
    acc[b] = a;
  }

  float tA = (q & 1) ? acc[0] : acc[2];
  float tB = (q & 1) ? acc[1] : acc[3];
  float rA = __shfl_xor(tA, 1, 4);
  float rB = __shfl_xor(tB, 1, 4);
  float u = (q & 1) ? (acc[2] + rA) : (acc[0] + rA);
  float v = (q & 1) ? (acc[3] + rB) : (acc[1] + rB);
  float tC = (q & 2) ? u : v;
  float rC = __shfl_xor(tC, 2, 4);
  float f = (q & 2) ? (v + rC) : (u + rC);
  int bmap = ((q & 1) << 1) | ((q & 2) >> 1);
  out[(size_t)bmap * NPTS + n] = f + decb;
}

extern "C" void kernel_launch(void* const* d_in, const int* in_sizes, int n_in,
                              void* d_out, int out_size, void* d_ws, size_t ws_size,
                              hipStream_t stream) {
  const float* x      = (const float*)d_in[0];
  const int*   nid    = (const int*)d_in[1];
  const float* nd     = (const float*)d_in[2];
  const int*   labels = (const int*)d_in[3];
  const float* enc1_w = (const float*)d_in[4];
  const float* enc1_b = (const float*)d_in[5];
  const float* enc2_w = (const float*)d_in[6];
  const float* enc2_b = (const float*)d_in[7];
  const float* dec_w  = (const float*)d_in[8];
  const float* dec_b  = (const float*)d_in[9];
  const float* h0_w   = (const float*)d_in[10];
  const float* h0_b   = (const float*)d_in[11];
  const float* h1_w   = (const float*)d_in[12];
  const float* h1_b   = (const float*)d_in[13];
  const float* h2_w   = (const float*)d_in[14];
  const float* h2_b   = (const float*)d_in[15];
  const float* Bp     = (const float*)d_in[16];
  float* out = (float*)d_out;
  float* ws  = (float*)d_ws;
  float* part  = ws;          // 200*20 = 4000 floats
  float* w_enc = ws + 4000;   // 64 floats
  float* w_hcl = ws + 4064;   // 256 floats
  float* z0g   = ws + 4320;   // 800 floats  [j][b]
  float* z1g   = ws + 5120;   // 800 floats  [r][b]
  unsigned int* bars = (unsigned int*)(ws + 5920);  // bar1, bar2

  hipMemsetAsync(bars, 0, 8, stream);
  k_enc1<<<ENC1_BLOCKS, 256, 0, stream>>>(x, enc1_w, part);
  k_mlpFused<<<MLP_BLOCKS, 256, 0, stream>>>(part, enc1_b, enc2_w, enc2_b,
                                             h0_w, h0_b, h1_w, h1_b, h2_w, h2_b,
                                             w_enc, w_hcl, z0g, z1g,
                                             bars, bars + 1);
  k_conv<<<CONV_BLOCKS, 256, 0, stream>>>(nid, nd, labels, dec_w, dec_b,
                                          Bp, w_enc, w_hcl, out);
}

// Round 13
// 36.930 us; speedup vs baseline: 1.2821x; 1.2821x over previous
//
#include <hip/hip_runtime.h>
#include <math.h>

#define NPTS 50000
#define KNBR 16
#define LAT  16
#define NCLS 64
#define NB   4

#define ENC1_CHUNKS 5
#define ENC1_BLOCKS (200 * ENC1_CHUNKS)      // 1000
#define NLANES (NPTS * 4)                    // 200000
#define CONV_BLOCKS ((NLANES + 255) / 256)   // 782

__device__ __forceinline__ float sigmoidf_(float v) { return 1.0f / (1.0f + expf(-v)); }

// ---------------- Kernel 1: x @ enc1_w.T partials ----------------
__global__ __launch_bounds__(256) void k_enc1(const float* __restrict__ x,
                                              const float* __restrict__ w,
                                              float* __restrict__ part) {
  const int NV4 = NPTS / 4;           // 12500 float4 per row
  const int CV  = NV4 / ENC1_CHUNKS;  // 2500 float4 per chunk
  int bid = blockIdx.x;
  int j = bid / ENC1_CHUNKS;
  int chunk = bid - j * ENC1_CHUNKS;
  int t = threadIdx.x;
  const float4* wv = (const float4*)(w + (size_t)j * NPTS);
  const float4* xv = (const float4*)x;
  float a0 = 0.f, a1 = 0.f, a2 = 0.f, a3 = 0.f;
  int vend = (chunk + 1) * CV;
#pragma unroll 2
  for (int v = chunk * CV + t; v < vend; v += 256) {
    float4 wf = wv[v];
    float4 x0 = xv[v];
    float4 x1 = xv[NV4 + v];
    float4 x2 = xv[2 * NV4 + v];
    float4 x3 = xv[3 * NV4 + v];
    a0 += wf.x * x0.x + wf.y * x0.y + wf.z * x0.z + wf.w * x0.w;
    a1 += wf.x * x1.x + wf.y * x1.y + wf.z * x1.z + wf.w * x1.w;
    a2 += wf.x * x2.x + wf.y * x2.y + wf.z * x2.z + wf.w * x2.w;
    a3 += wf.x * x3.x + wf.y * x3.y + wf.z * x3.z + wf.w * x3.w;
  }
#pragma unroll
  for (int off = 32; off > 0; off >>= 1) {
    a0 += __shfl_down(a0, off);
    a1 += __shfl_down(a1, off);
    a2 += __shfl_down(a2, off);
    a3 += __shfl_down(a3, off);
  }
  __shared__ float red[4][4];
  int wid = t >> 6;
  if ((t & 63) == 0) {
    red[wid][0] = a0; red[wid][1] = a1; red[wid][2] = a2; red[wid][3] = a3;
  }
  __syncthreads();
  if (t < 4) {
    float s = red[0][t] + red[1][t] + red[2][t] + red[3][t];
    part[j * 20 + chunk * 4 + t] = s;
  }
}

// ---------------- Kernel 2a: MLP stages A-C, weights staged to LDS upfront ----------------
__global__ __launch_bounds__(1024) void k_mlpABC(const float* __restrict__ part,
                                                 const float* __restrict__ enc1_b,
                                                 const float* __restrict__ enc2_w,
                                                 const float* __restrict__ enc2_b,
                                                 const float* __restrict__ h0_w,
                                                 const float* __restrict__ h0_b,
                                                 float* __restrict__ w_enc,
                                                 float* __restrict__ z0g) {
  __shared__ __align__(16) float4 s_e2w[800];      // enc2_w, linear float4
  __shared__ __align__(16) float s_h0w[200 * 20];  // h0_w row jo at [jo*20..+16), 80B pitch
  __shared__ float s_h[NB][200];
  __shared__ float s_enc[NB][LAT];
  int t = threadIdx.x;

  // ---- Stage weights (loads issued first; overlap with A's part loads) ----
  if (t < 800) {
    float4 we = ((const float4*)enc2_w)[t];
    float4 wh = ((const float4*)h0_w)[t];
    s_e2w[t] = we;
    int jo = t >> 2, c = t & 3;
    *(float4*)&s_h0w[jo * 20 + c * 4] = wh;
  }

  // ---- A: h = sigmoid(sum of 5 chunk partials + bias) ----
  if (t < 800) {
    int j = t >> 2, b = t & 3;
    float v = part[j * 20 + 0 + b] + part[j * 20 + 4 + b] + part[j * 20 + 8 + b] +
              part[j * 20 + 12 + b] + part[j * 20 + 16 + b] + enc1_b[j];
    s_h[b][j] = sigmoidf_(v);
  }
  __syncthreads();

  // ---- B: encoded = h @ enc2_w.T + enc2_b  (64 outputs x 16 lanes, LDS weights) ----
  {
    int g = t >> 4, p = t & 15;      // g: 0..63
    int b = g >> 4, i = g & 15;
    float s = 0.f;
    for (int f = p; f < 50; f += 16) {
      float4 w = s_e2w[i * 50 + f];
      int j = f * 4;
      s += w.x * s_h[b][j] + w.y * s_h[b][j + 1] + w.z * s_h[b][j + 2] + w.w * s_h[b][j + 3];
    }
    s += __shfl_xor(s, 1, 16);
    s += __shfl_xor(s, 2, 16);
    s += __shfl_xor(s, 4, 16);
    s += __shfl_xor(s, 8, 16);
    if (p == 0) {
      s += enc2_b[i];
      s_enc[b][i] = s;
      w_enc[b * LAT + i] = s;
    }
  }
  __syncthreads();

  // ---- C: z0 = swish(encoded @ h0_w.T + h0_b); write z0g[j*4+b] (LDS weights) ----
  if (t < 800) {
    int jo = t >> 2, b = t & 3;
    const float* hw = &s_h0w[jo * 20];
    float4 w0 = *(const float4*)&hw[0];
    float4 w1 = *(const float4*)&hw[4];
    float4 w2 = *(const float4*)&hw[8];
    float4 w3 = *(const float4*)&hw[12];
    float s = h0_b[jo];
    s += w0.x * s_enc[b][0] + w0.y * s_enc[b][1] + w0.z * s_enc[b][2] + w0.w * s_enc[b][3];
    s += w1.x * s_enc[b][4] + w1.y * s_enc[b][5] + w1.z * s_enc[b][6] + w1.w * s_enc[b][7];
    s += w2.x * s_enc[b][8] + w2.y * s_enc[b][9] + w2.z * s_enc[b][10] + w2.w * s_enc[b][11];
    s += w3.x * s_enc[b][12] + w3.y * s_enc[b][13] + w3.z * s_enc[b][14] + w3.w * s_enc[b][15];
    z0g[jo * 4 + b] = s * sigmoidf_(s);   // [j][b] flat
  }
}

// ---------------- Kernel 2b: stage D ----------------
__global__ __launch_bounds__(256) void k_mlpD(const float* __restrict__ z0g,
                                              const float* __restrict__ h1_w,
                                              const float* __restrict__ h1_b,
                                              float* __restrict__ z1g) {
  __shared__ __align__(16) float4 s_z0[200];   // [j] -> 4 batches
  int t = threadIdx.x;
  for (int o = t; o < 200; o += 256) s_z0[o] = ((const float4*)z0g)[o];
  __syncthreads();

  int row = blockIdx.x * 4 + (t >> 6);
  int l = t & 63;
  float d0 = 0.f, d1 = 0.f, d2 = 0.f, d3 = 0.f;
  if (l < 50) {
    float4 w = ((const float4*)(h1_w + row * 200))[l];
    float4 z0 = s_z0[4 * l + 0], z1 = s_z0[4 * l + 1];
    float4 z2 = s_z0[4 * l + 2], z3 = s_z0[4 * l + 3];
    d0 = w.x * z0.x + w.y * z1.x + w.z * z2.x + w.w * z3.x;
    d1 = w.x * z0.y + w.y * z1.y + w.z * z2.y + w.w * z3.y;
    d2 = w.x * z0.z + w.y * z1.z + w.z * z2.z + w.w * z3.z;
    d3 = w.x * z0.w + w.y * z1.w + w.z * z2.w + w.w * z3.w;
  }
#pragma unroll
  for (int m = 32; m > 0; m >>= 1) {
    d0 += __shfl_xor(d0, m, 64);
    d1 += __shfl_xor(d1, m, 64);
    d2 += __shfl_xor(d2, m, 64);
    d3 += __shfl_xor(d3, m, 64);
  }
  if (l == 0) {
    float bb = h1_b[row];
    float s;
    s = d0 + bb; z1g[row * 4 + 0] = s * sigmoidf_(s);
    s = d1 + bb; z1g[row * 4 + 1] = s * sigmoidf_(s);
    s = d2 + bb; z1g[row * 4 + 2] = s * sigmoidf_(s);
    s = d3 + bb; z1g[row * 4 + 3] = s * sigmoidf_(s);
  }
}

// ---------------- Kernel 2c: stage E ----------------
__global__ __launch_bounds__(256) void k_mlpE(const float* __restrict__ z1g,
                                              const float* __restrict__ h2_w,
                                              const float* __restrict__ h2_b,
                                              float* __restrict__ w_hcl) {
  __shared__ __align__(16) float4 s_z1[200];
  int t = threadIdx.x;
  for (int o = t; o < 200; o += 256) s_z1[o] = ((const float4*)z1g)[o];
  __syncthreads();

  int c = blockIdx.x * 4 + (t >> 6);
  int l = t & 63;
  float e0 = 0.f, e1 = 0.f, e2 = 0.f, e3 = 0.f;
  if (l < 50) {
    float4 w = ((const float4*)(h2_w + c * 200))[l];
    float4 za = s_z1[4 * l + 0], zb = s_z1[4 * l + 1];
    float4 zc = s_z1[4 * l + 2], zd = s_z1[4 * l + 3];
    e0 = w.x * za.x + w.y * zb.x + w.z * zc.x + w.w * zd.x;
    e1 = w.x * za.y + w.y * zb.y + w.z * zc.y + w.w * zd.y;
    e2 = w.x * za.z + w.y * zb.z + w.z * zc.z + w.w * zd.z;
    e3 = w.x * za.w + w.y * zb.w + w.z * zc.w + w.w * zd.w;
  }
#pragma unroll
  for (int m = 32; m > 0; m >>= 1) {
    e0 += __shfl_xor(e0, m, 64);
    e1 += __shfl_xor(e1, m, 64);
    e2 += __shfl_xor(e2, m, 64);
    e3 += __shfl_xor(e3, m, 64);
  }
  if (l == 0) {
    float sb = h2_b[c];
    w_hcl[0 * NCLS + c] = sigmoidf_(0.01f * (e0 + sb));
    w_hcl[1 * NCLS + c] = sigmoidf_(0.01f * (e1 + sb));
    w_hcl[2 * NCLS + c] = sigmoidf_(0.01f * (e2 + sb));
    w_hcl[3 * NCLS + c] = sigmoidf_(0.01f * (e3 + sb));
  }
}

// ---------------- Kernel 3: neighbour conv (occupancy cap 128 VGPR) ----------------
__global__ __launch_bounds__(256, 4) void k_conv(const int* __restrict__ nid,
                                                 const float* __restrict__ nd,
                                                 const int* __restrict__ labels,
                                                 const float* __restrict__ dec_w,
                                                 const float* __restrict__ dec_b,
                                                 const float* __restrict__ Bp,
                                                 const float* __restrict__ w_enc,
                                                 const float* __restrict__ w_hcl,
                                                 float* __restrict__ out) {
  __shared__ float s_enc[NB * LAT];
  __shared__ float s_hcl[NB * NCLS];
  int t = threadIdx.x;
  if (t < NB * LAT) s_enc[t] = w_enc[t];
  s_hcl[t] = w_hcl[t];
  __syncthreads();

  int gidx = blockIdx.x * 256 + t;       // = n*4 + q
  int n = gidx >> 2;
  int q = t & 3;
  if (n >= NPTS) return;

  const float4* nd4 = (const float4*)nd + (size_t)n * 4;
  const int4*   ni4 = (const int4*)nid + (size_t)n * 4;
  float dA[16];
  int nA[16];
#pragma unroll
  for (int a = 0; a < 4; ++a) {
    float4 v = nd4[a];
    int4  iv = ni4[a];
    dA[a * 4 + 0] = v.x * v.x; dA[a * 4 + 1] = v.y * v.y;
    dA[a * 4 + 2] = v.z * v.z; dA[a * 4 + 3] = v.w * v.w;
    nA[a * 4 + 0] = iv.x; nA[a * 4 + 1] = iv.y;
    nA[a * 4 + 2] = iv.z; nA[a * 4 + 3] = iv.w;
  }

  int lab = labels[n];
  float decb = dec_b[n];
  float Bv = Bp[0];

  const float4* dw4 = (const float4*)dec_w;
  float4 dwp[8];
#pragma unroll
  for (int k = 0; k < 8; ++k)
    dwp[k] = dw4[(size_t)nA[k] * 4 + q];

  float inv0 = 1.0f / (4.0f * Bv * Bv);

  float ivd[4][4];
#pragma unroll
  for (int b = 0; b < 4; ++b) {
    float H = s_hcl[b * NCLS + lab];
    float base = 1.0f - 0.5f * H;
    float rb = __builtin_amdgcn_rcpf(base * base);   // base^-2
    float rb2 = rb * rb;
    float rb4 = rb2 * rb2;
    float rb8 = rb4 * rb4;
    float start = inv0;
    if (q & 1) start *= rb4;
    if (q & 2) start *= rb8;
    ivd[b][0] = start;
    ivd[b][1] = ivd[b][0] * rb;
    ivd[b][2] = ivd[b][1] * rb;
    ivd[b][3] = ivd[b][2] * rb;
  }

  float sden[4][4], num[4][4];
#pragma unroll
  for (int b = 0; b < 4; ++b)
#pragma unroll
    for (int j = 0; j < 4; ++j) { sden[b][j] = 0.f; num[b][j] = 0.f; }

#pragma unroll
  for (int k = 0; k < KNBR; ++k) {
    float4 dw = (k < 8) ? dwp[k] : dw4[(size_t)nA[k] * 4 + q];
    float d2k = dA[k];
#pragma unroll
    for (int b = 0; b < 4; ++b) {
      float w0 = fmaxf(fmaf(-d2k, ivd[b][0], 1.0f), 0.0f);
      float w1 = fmaxf(fmaf(-d2k, ivd[b][1], 1.0f), 0.0f);
      float w2 = fmaxf(fmaf(-d2k, ivd[b][2], 1.0f), 0.0f);
      float w3 = fmaxf(fmaf(-d2k, ivd[b][3], 1.0f), 0.0f);
      sden[b][0] += w0; num[b][0] = fmaf(w0, dw.x, num[b][0]);
      sden[b][1] += w1; num[b][1] = fmaf(w1, dw.y, num[b][1]);
      sden[b][2] += w2; num[b][2] = fmaf(w2, dw.z, num[b][2]);
      sden[b][3] += w3; num[b][3] = fmaf(w3, dw.w, num[b][3]);
    }
  }

  float acc[4];
#pragma unroll
  for (int b = 0; b < 4; ++b) {
    float a = 0.f;
#pragma unroll
    for (int j = 0; j < 4; ++j) {
      a = fmaf(s_enc[b * LAT + q * 4 + j] * __builtin_amdgcn_rcpf(sden[b][j]),
               num[b][j], a);
    }
    acc[b] = a;
  }

  float tA = (q & 1) ? acc[0] : acc[2];
  float tB = (q & 1) ? acc[1] : acc[3];
  float rA = __shfl_xor(tA, 1, 4);
  float rB = __shfl_xor(tB, 1, 4);
  float u = (q & 1) ? (acc[2] + rA) : (acc[0] + rA);
  float v = (q & 1) ? (acc[3] + rB) : (acc[1] + rB);
  float tC = (q & 2) ? u : v;
  float rC = __shfl_xor(tC, 2, 4);
  float f = (q & 2) ? (v + rC) : (u + rC);
  int bmap = ((q & 1) << 1) | ((q & 2) >> 1);
  out[(size_t)bmap * NPTS + n] = f + decb;
}

extern "C" void kernel_launch(void* const* d_in, const int* in_sizes, int n_in,
                              void* d_out, int out_size, void* d_ws, size_t ws_size,
                              hipStream_t stream) {
  const float* x      = (const float*)d_in[0];
  const int*   nid    = (const int*)d_in[1];
  const float* nd     = (const float*)d_in[2];
  const int*   labels = (const int*)d_in[3];
  const float* enc1_w = (const float*)d_in[4];
  const float* enc1_b = (const float*)d_in[5];
  const float* enc2_w = (const float*)d_in[6];
  const float* enc2_b = (const float*)d_in[7];
  const float* dec_w  = (const float*)d_in[8];
  const float* dec_b  = (const float*)d_in[9];
  const float* h0_w   = (const float*)d_in[10];
  const float* h0_b   = (const float*)d_in[11];
  const float* h1_w   = (const float*)d_in[12];
  const float* h1_b   = (const float*)d_in[13];
  const float* h2_w   = (const float*)d_in[14];
  const float* h2_b   = (const float*)d_in[15];
  const float* Bp     = (const float*)d_in[16];
  float* out = (float*)d_out;
  float* ws  = (float*)d_ws;
  float* part  = ws;          // 200*20 = 4000 floats
  float* w_enc = ws + 4000;   // 64 floats
  float* w_hcl = ws + 4064;   // 256 floats
  float* z0g   = ws + 4320;   // 800 floats  [j][b]
  float* z1g   = ws + 5120;   // 800 floats  [r][b]

  k_enc1<<<ENC1_BLOCKS, 256, 0, stream>>>(x, enc1_w, part);
  k_mlpABC<<<1, 1024, 0, stream>>>(part, enc1_b, enc2_w, enc2_b, h0_w, h0_b,
                                   w_enc, z0g);
  k_mlpD<<<50, 256, 0, stream>>>(z0g, h1_w, h1_b, z1g);
  k_mlpE<<<16, 256, 0, stream>>>(z1g, h2_w, h2_b, w_hcl);
  k_conv<<<CONV_BLOCKS, 256, 0, stream>>>(nid, nd, labels, dec_w, dec_b,
                                          Bp, w_enc, w_hcl, out);
}